// Round 6
// baseline (121.912 us; speedup 1.0000x reference)
//
#include <hip/hip_runtime.h>

typedef __attribute__((ext_vector_type(8))) short short8;
typedef __attribute__((ext_vector_type(4))) float floatx4;

#define FDIM 512
#define HDIM 256

__device__ __forceinline__ unsigned short f2bf(float f) {
  unsigned int u = __float_as_uint(f);
  u += 0x7fffu + ((u >> 16) & 1u);   // round-to-nearest-even
  return (unsigned short)(u >> 16);
}

__device__ __forceinline__ short8 pack2(floatx4 a, floatx4 b) {
  short8 r;
  r[0] = (short)f2bf(a[0]); r[1] = (short)f2bf(a[1]);
  r[2] = (short)f2bf(a[2]); r[3] = (short)f2bf(a[3]);
  r[4] = (short)f2bf(b[0]); r[5] = (short)f2bf(b[1]);
  r[6] = (short)f2bf(b[2]); r[7] = (short)f2bf(b[3]);
  return r;
}

__device__ __forceinline__ float fast_tanh(float x) {
  x = fminf(15.0f, fmaxf(-15.0f, x));
  float e = __expf(2.0f * x);
  return (e - 1.0f) / (e + 1.0f);
}

// A: 2 x global_load_dwordx4 (8 floats), counted in the manual vmcnt ledger.
#define GLOAD_A(r0, r1, p)                                                     \
  do {                                                                         \
    asm volatile("global_load_dwordx4 %0, %1, off"                             \
                 : "=v"(r0) : "v"(p) : "memory");                              \
    asm volatile("global_load_dwordx4 %0, %1, off offset:16"                   \
                 : "=v"(r1) : "v"(p) : "memory");                              \
  } while (0)

// B: 4 x global_load_dwordx4 (4 short8 fragments, 16-col stride = 256 B).
#define GLOAD_B(r, p)                                                          \
  do {                                                                         \
    asm volatile("global_load_dwordx4 %0, %1, off"                             \
                 : "=v"(r[0]) : "v"(p) : "memory");                            \
    asm volatile("global_load_dwordx4 %0, %1, off offset:256"                  \
                 : "=v"(r[1]) : "v"(p) : "memory");                            \
    asm volatile("global_load_dwordx4 %0, %1, off offset:512"                  \
                 : "=v"(r[2]) : "v"(p) : "memory");                            \
    asm volatile("global_load_dwordx4 %0, %1, off offset:768"                  \
                 : "=v"(r[3]) : "v"(p) : "memory");                            \
  } while (0)

// K0: pack W1 [512][256] fp32 -> W1B bf16 fragment-major:
// element index = s*8192 + oct*2048 + n*8 + e   (k = s*32 + oct*8 + e)
// Blocks < 128 also zero out (re-poison safety; out accumulated by atomics).
__global__ void __launch_bounds__(256)
k0_pack_w1(const float* __restrict__ W1, unsigned short* __restrict__ W1B,
           float* __restrict__ out) {
  int tid = threadIdx.x;
  int idx = blockIdx.x * 256 + tid;           // 0..131071
  if (blockIdx.x < 128) out[blockIdx.x * 256 + tid] = 0.0f;   // 32768 floats
  int k = idx >> 8;                           // 0..511
  int n = idx & 255;
  int s = k >> 5, r = k & 31, oct = r >> 3, e = r & 7;
  W1B[s * 8192 + oct * 2048 + n * 8 + e] = f2bf(W1[idx]);
}

// K1 fused-light: scores + exp + UNNORMALIZED per-bag weighted sum.
// Phase 1 (R5-proven): 64 rows/block, 4 waves, BK=32, 16 steps, LDS ~9.5 KB,
// B in registers, counted-vmcnt pipeline -> ~3 independent blocks/CU.
// Phase 2 (NEW): NO X retention — after scores, the block RE-READS its own
// 64x512 fp32 rows from global (L2/L3-hot: read by phase 1 a few µs ago,
// only ~30-50 MB streams device-wide in between, L3 = 256 MB) and atomically
// accumulates es-weighted sums into out. Overlaps other blocks' phase 1 on
// the same CU instead of running as a serial tail kernel.
// SPILL SAFETY (round-4 lesson): no min-waves cap below demand — spilled
// in-flight asm-load regs + scratch vmcnt ops silently corrupt the ledger.
// vmcnt ledger (per thread, in-order; A=2 instr, B=4 instr, B depth-1,
// A depth-2):  prologue: A(0) B(0) A(1) = 8 outstanding.
//   step t head: [A(t)2 B(t)4 A(t+1)2] -> vmcnt(6) retires A(t)
//     (t=15: [A15 B15] -> vmcnt(4))
//   after barrier: issue B(t+1) (t<15) then A(t+2) (t<14) -> 12 outstanding
//   compute wait: vmcnt(8) retires B(t)   (t=14: vmcnt(6); t=15: vmcnt(0))
// WAR on As[t&1]: readers of step t-2 drain via own lgkmcnt(0) before
// barrier(t-1); writer passes barrier(t-1) first -> one barrier/step safe.
__global__ void __launch_bounds__(256, 2)
k1_fused(const float* __restrict__ X,
         const unsigned short* __restrict__ W1B,
         const float* __restrict__ b1,
         const float* __restrict__ W2,
         const int* __restrict__ bag_sizes,
         int nbags,
         float* __restrict__ out,
         float* __restrict__ partials) {
  __shared__ __align__(16) unsigned short As[2][2048];  // [buf][row64*32k] = 8 KB
  __shared__ float scpart[256];                         // [wn][row64]
  __shared__ float es_s[64];

  const int tid  = threadIdx.x;
  const int wn   = tid >> 6;          // 0..3 col-group
  const int lane = tid & 63;
  const int l15  = lane & 15;
  const int l4   = lane >> 4;
  const long row0 = (long)blockIdx.x * 64;

  floatx4 acc[4][4];
  #pragma unroll
  for (int m = 0; m < 4; m++)
    #pragma unroll
    for (int n = 0; n < 4; n++)
      acc[m][n] = (floatx4){0.f, 0.f, 0.f, 0.f};

  // A staging map: thread -> (row = tid>>2, octet = tid&3 -> 8 consecutive k)
  const int arow = tid >> 2;                    // 0..63
  const int aoct = tid & 3;                     // octet within 32-k step
  const float* xsrc = X + (row0 + arow) * FDIM + aoct * 8;
  // B fragment base for this lane: oct = l4, col = wn*64 + l15
  const unsigned short* bsrc = W1B + l4 * 2048 + (wn * 64 + l15) * 8;

  floatx4 va0, va1, vb0, vb1;            // 2 rotating A sets (depth-2)
  short8 br0[4], br1[4];                 // 2 rotating B sets (depth-1)

  // Prologue issue order: A(0), B(0)->set0, A(1)  => 8 outstanding
  GLOAD_A(va0, va1, xsrc);
  GLOAD_B(br0, bsrc);
  GLOAD_A(vb0, vb1, xsrc + 32);

  #pragma unroll
  for (int t = 0; t < 16; ++t) {
    // ---- retire A(t) regs ----
    if (t < 15) asm volatile("s_waitcnt vmcnt(6)" ::: "memory");
    else        asm volatile("s_waitcnt vmcnt(4)" ::: "memory");
    __builtin_amdgcn_sched_barrier(0);
    {
      short8 a = ((t & 1) == 0) ? pack2(va0, va1) : pack2(vb0, vb1);
      *(short8*)(&As[t & 1][arow * 32 + aoct * 8]) = a;
    }
    asm volatile("s_waitcnt lgkmcnt(0)" ::: "memory");
    __builtin_amdgcn_sched_barrier(0);
    __builtin_amdgcn_s_barrier();
    // ---- issue next loads (stay in flight across barriers) ----
    if (t < 15) {                       // B(t+1) -> other set
      const unsigned short* bp = bsrc + (t + 1) * 8192;
      if (((t + 1) & 1) == 0) GLOAD_B(br0, bp);
      else                    GLOAD_B(br1, bp);
    }
    if (t < 14) {                       // A(t+2) -> just-consumed set
      const float* pp = xsrc + (t + 2) * 32;
      if ((t & 1) == 0) GLOAD_A(va0, va1, pp);
      else              GLOAD_A(vb0, vb1, pp);
    }
    // ---- retire B(t) regs ----
    if (t < 14)       asm volatile("s_waitcnt vmcnt(8)" ::: "memory");
    else if (t == 14) asm volatile("s_waitcnt vmcnt(6)" ::: "memory");
    else              asm volatile("s_waitcnt vmcnt(0)" ::: "memory");
    __builtin_amdgcn_sched_barrier(0);
    // ---- compute(t): 4 A-frags x 4 B-frags, 16 MFMA per wave ----
    short8 af[4];
    #pragma unroll
    for (int m = 0; m < 4; ++m)
      af[m] = *(const short8*)(&As[t & 1][(m * 16 + l15) * 32 + l4 * 8]);
    const short8* bcur = ((t & 1) == 0) ? br0 : br1;
    #pragma unroll
    for (int n = 0; n < 4; ++n)
      #pragma unroll
      for (int m = 0; m < 4; ++m)
        acc[m][n] = __builtin_amdgcn_mfma_f32_16x16x32_bf16(af[m], bcur[n], acc[m][n], 0, 0, 0);
  }

  // epilogue: score = sum_c tanh(H + b1[c]) * W2[c]  over this wave's 64 cols
  float rowacc[16];
  #pragma unroll
  for (int i = 0; i < 16; i++) rowacc[i] = 0.f;
  #pragma unroll
  for (int n = 0; n < 4; n++) {
    int c = wn * 64 + n * 16 + l15;
    float b1c = b1[c];
    float w2c = W2[c];
    #pragma unroll
    for (int m = 0; m < 4; m++)
      #pragma unroll
      for (int j = 0; j < 4; j++) {
        float h = fast_tanh(acc[m][n][j] + b1c);
        rowacc[m * 4 + j] = fmaf(h, w2c, rowacc[m * 4 + j]);
      }
  }
  #pragma unroll
  for (int i = 0; i < 16; i++) {
    float v = rowacc[i];
    v += __shfl_xor(v, 1, 64);
    v += __shfl_xor(v, 2, 64);
    v += __shfl_xor(v, 4, 64);
    v += __shfl_xor(v, 8, 64);
    rowacc[i] = v;
  }
  if (l15 == 0) {
    #pragma unroll
    for (int m = 0; m < 4; m++)
      #pragma unroll
      for (int j = 0; j < 4; j++)
        scpart[wn * 64 + m * 16 + l4 * 4 + j] = rowacc[m * 4 + j];
  }
  __syncthreads();

  // es (LDS) + block partial Z  (first wave only)
  if (tid < 64) {
    float sv = scpart[0 * 64 + tid] + scpart[1 * 64 + tid] +
               scpart[2 * 64 + tid] + scpart[3 * 64 + tid];
    float ev = __expf(sv);
    es_s[tid] = ev;
    float v = ev;
    v += __shfl_xor(v, 1, 64);
    v += __shfl_xor(v, 2, 64);
    v += __shfl_xor(v, 4, 64);
    v += __shfl_xor(v, 8, 64);
    v += __shfl_xor(v, 16, 64);
    v += __shfl_xor(v, 32, 64);
    if (tid == 0) partials[blockIdx.x] = v;
  }
  __syncthreads();   // es_s visible; all As reads long done (red4 aliases As)

  // ---- phase 2: out[bag] += sum_r es_s[r] * X[row0+r]  (unnormalized) ----
  // 256 threads = 128 feature-float4 x 2 row-parities; X rows L2/L3-hot.
  float4* red4 = (float4*)As;          // 2 KB reduction scratch (As is dead)
  const int f = (tid & 127) * 4;       // 0..508
  const int r = tid >> 7;              // 0 or 1

  // bag of first row (uniform across block)
  int bag = 0; long cum = 0;
  while (bag + 1 < nbags && cum + (long)bag_sizes[bag] <= row0) {
    cum += bag_sizes[bag]; ++bag;
  }
  long bagEnd = cum + (long)bag_sizes[bag];

  int rs = 0;
  while (rs < 64) {                    // uniform trip count across block
    int se = (int)(bagEnd - row0 < 64 ? bagEnd - row0 : 64);
    if (se < rs) se = rs;
    float ax = 0.f, ay = 0.f, az = 0.f, aw = 0.f;
    for (int i = rs + r; i < se; i += 2) {
      float w = es_s[i];
      float4 x = *(const float4*)(X + (row0 + i) * FDIM + f);
      ax = fmaf(x.x, w, ax); ay = fmaf(x.y, w, ay);
      az = fmaf(x.z, w, az); aw = fmaf(x.w, w, aw);
    }
    if (r == 1) red4[tid & 127] = (float4){ax, ay, az, aw};
    __syncthreads();
    if (r == 0 && se > rs) {
      float4 o = red4[tid];
      float* op = out + (long)bag * FDIM + f;
      atomicAdd(op + 0, ax + o.x); atomicAdd(op + 1, ay + o.y);
      atomicAdd(op + 2, az + o.z); atomicAdd(op + 3, aw + o.w);
    }
    __syncthreads();                   // red4 reusable next segment
    rs = se;
    if (rs < 64) {
      ++bag;
      if (bag >= nbags) { bagEnd = row0 + 64; bag = nbags - 1; }
      else bagEnd += (long)bag_sizes[bag];
    }
  }
}

// K2: Z = sum(partials) (redundant per block); out *= 1/Z
__global__ void __launch_bounds__(256)
k2_scale(const float* __restrict__ partials, int nparts, float* __restrict__ out) {
  __shared__ float wred[4];
  int tid = threadIdx.x;
  float sL = 0.f;
  for (int j = tid; j < nparts; j += 256) sL += partials[j];
  #pragma unroll
  for (int m = 1; m < 64; m <<= 1) sL += __shfl_xor(sL, m, 64);
  if ((tid & 63) == 0) wred[tid >> 6] = sL;
  __syncthreads();
  float invZ = 1.0f / (wred[0] + wred[1] + wred[2] + wred[3]);
  int i = blockIdx.x * 256 + tid;
  out[i] = out[i] * invZ;
}

extern "C" void kernel_launch(void* const* d_in, const int* in_sizes, int n_in,
                              void* d_out, int out_size, void* d_ws, size_t ws_size,
                              hipStream_t stream) {
  const float* X         = (const float*)d_in[0];
  const int*   bag_sizes = (const int*)d_in[1];
  const float* W1        = (const float*)d_in[2];
  const float* b1        = (const float*)d_in[3];
  const float* W2        = (const float*)d_in[4];
  // b2 (d_in[5]) cancels in the global softmax — unused.
  float* out = (float*)d_out;

  const int T     = in_sizes[0] / FDIM;   // 131072
  const int nbags = in_sizes[1];          // 64
  const int nblk  = T / 64;               // 2048

  char* ws = (char*)d_ws;
  unsigned short* W1B = (unsigned short*)ws;                     // 262144 B
  float* partials = (float*)(ws + 262144);                       // 8192 B

  hipLaunchKernelGGL(k0_pack_w1, dim3(512), dim3(256), 0, stream, W1, W1B, out);
  hipLaunchKernelGGL(k1_fused, dim3(nblk), dim3(256), 0, stream,
                     X, W1B, b1, W2, bag_sizes, nbags, out, partials);
  hipLaunchKernelGGL(k2_scale, dim3((nbags * FDIM) / 256), dim3(256), 0, stream,
                     partials, nblk, out);
}